// Round 2
// baseline (14339.531 us; speedup 1.0000x reference)
//
#include <hip/hip_runtime.h>
#include <hip/hip_bf16.h>

// ---------------------------------------------------------------------------
// Decision-Transformer forward, MI355X (round 1: all tensors are FLOAT32 —
// the reference's setup_inputs() is explicitly jnp.float32; round-0 read them
// as bf16 which produced Inf/NaN).
// L=6, H=16, C=1024, T=256, S=3T=768, B=4, D_FF=4096, NACT=80.
// ---------------------------------------------------------------------------

#define S_LEN 768
#define C_DIM 1024
#define NHEAD 16
#define HDIM 64
#define BATCH 4
#define TCTX 256
#define DFF 4096
#define NACT 80
#define MROWS (BATCH * S_LEN)   // 3072

// ---------------------------------------------------------------------------
// Embedding: one block per (b,t). CNN encoder + meta MLP + rtg + action emb,
// interleave tokens, add positional embeddings. Writes X (f32, B*S x C).
// ---------------------------------------------------------------------------
__global__ __launch_bounds__(256) void embed_kernel(
    const float* __restrict__ states, const float* __restrict__ rtgs,
    const float* __restrict__ meta,
    const float* __restrict__ c1w, const float* __restrict__ c1b,
    const float* __restrict__ c2w, const float* __restrict__ c2b,
    const float* __restrict__ c3w, const float* __restrict__ c3b,
    const float* __restrict__ encw, const float* __restrict__ encb,
    const float* __restrict__ mw1, const float* __restrict__ mb1,
    const float* __restrict__ mw2, const float* __restrict__ mb2,
    const float* __restrict__ retw, const float* __restrict__ retb,
    const float* __restrict__ aemb, const float* __restrict__ pos,
    const float* __restrict__ gpos,
    const int* __restrict__ actions, const int* __restrict__ timesteps,
    float* __restrict__ X)
{
    const int n = blockIdx.x;          // b*T + t
    const int b = n >> 8, t = n & 255;
    const int tid = threadIdx.x;

    __shared__ float sin_[640];
    __shared__ float h1[96];   // [o][oh][ow] -> o*6 + oh*3 + ow   (16,2,3)
    __shared__ float h2[32];
    __shared__ float feat[16];
    __shared__ float hidm[32];
    __shared__ float mer[4];

    for (int e = tid; e < 640; e += 256)
        sin_[e] = states[(size_t)n * 640 + e];
    __syncthreads();

    // conv1: (8ch,8,10) -> (16,2,3), k=8, s=2, p=1
    if (tid < 96) {
        int o = tid / 6, rem = tid % 6, oh = rem / 3, ow = rem % 3;
        float a = c1b[o];
        for (int ci = 0; ci < 8; ++ci)
            for (int kh = 0; kh < 8; ++kh) {
                int ih = oh * 2 - 1 + kh;
                if (ih < 0 || ih >= 8) continue;
                for (int kw = 0; kw < 8; ++kw) {
                    int iw = ow * 2 - 1 + kw;
                    if (iw < 0 || iw >= 10) continue;
                    a += c1w[((o * 8 + ci) * 8 + kh) * 8 + kw] * sin_[ci * 80 + ih * 10 + iw];
                }
            }
        h1[tid] = fmaxf(a, 0.f);
    }
    // meta MLP hidden (independent of conv chain)
    if (tid < 32) {
        float a = mb1[tid];
        for (int i = 0; i < 4; ++i)
            a += meta[(size_t)n * 4 + i] * mw1[i * 32 + tid];
        hidm[tid] = fmaxf(a, 0.f);
    }
    __syncthreads();

    // conv2: (16,2,3) -> (32,1,1), k=4, s=2, p=1
    if (tid < 32) {
        float a = c2b[tid];
        for (int ci = 0; ci < 16; ++ci)
            for (int kh = 0; kh < 4; ++kh) {
                int ih = -1 + kh;
                if (ih < 0 || ih >= 2) continue;
                for (int kw = 0; kw < 4; ++kw) {
                    int iw = -1 + kw;
                    if (iw < 0 || iw >= 3) continue;
                    a += c2w[((tid * 16 + ci) * 4 + kh) * 4 + kw] * h1[ci * 6 + ih * 3 + iw];
                }
            }
        h2[tid] = fmaxf(a, 0.f);
    }
    __syncthreads();

    // conv3: (32,1,1) -> (16,1,1), k=3, p=1 -> only center tap [1][1]
    if (tid < 16) {
        float a = c3b[tid];
        for (int ci = 0; ci < 32; ++ci)
            a += c3w[(tid * 32 + ci) * 9 + 4] * h2[ci];
        feat[tid] = fmaxf(a, 0.f);
    }
    // meta out (no relu on output)
    if (tid < 4) {
        float a = mb2[tid];
        for (int j = 0; j < 32; ++j) a += hidm[j] * mw2[j * 4 + tid];
        mer[tid] = a;
    }
    __syncthreads();

    const float r = rtgs[n];
    const int a_idx = actions[n];
    const int g = timesteps[b];
    const size_t xbase = ((size_t)b * S_LEN + 3 * t) * C_DIM;

    for (int c = tid; c < C_DIM; c += 256) {
        float se;
        if (c < 1020) {
            float acc = encb[c];
            #pragma unroll
            for (int k = 0; k < 16; ++k) acc += feat[k] * encw[k * 1020 + c];
            se = acc;
        } else {
            se = mer[c - 1020];
        }
        const float st = tanhf(se);
        const float rt = tanhf(r * retw[c] + retb[c]);
        const float ae = aemb[(size_t)a_idx * C_DIM + c];
        const float gp = gpos[(size_t)g * C_DIM + c];
        X[xbase + c]             = rt + gp + pos[(size_t)(3 * t + 0) * C_DIM + c];
        X[xbase + C_DIM + c]     = st + gp + pos[(size_t)(3 * t + 1) * C_DIM + c];
        X[xbase + 2 * C_DIM + c] = ae + gp + pos[(size_t)(3 * t + 2) * C_DIM + c];
    }
}

// ---------------------------------------------------------------------------
// LayerNorm over last dim (1024). One block per row.
// ---------------------------------------------------------------------------
__global__ __launch_bounds__(256) void ln_kernel(
    const float* __restrict__ in, float* __restrict__ out,
    const float* __restrict__ gw, const float* __restrict__ bw)
{
    const int row = blockIdx.x, tid = threadIdx.x;
    __shared__ float red[256];
    const float* x = in + (size_t)row * C_DIM;

    float v[4];
    float s = 0.f;
    #pragma unroll
    for (int j = 0; j < 4; ++j) { v[j] = x[tid + j * 256]; s += v[j]; }
    red[tid] = s; __syncthreads();
    for (int st = 128; st > 0; st >>= 1) { if (tid < st) red[tid] += red[tid + st]; __syncthreads(); }
    const float mean = red[0] * (1.0f / 1024.0f);
    __syncthreads();

    float s2 = 0.f;
    #pragma unroll
    for (int j = 0; j < 4; ++j) { float d = v[j] - mean; s2 += d * d; }
    red[tid] = s2; __syncthreads();
    for (int st = 128; st > 0; st >>= 1) { if (tid < st) red[tid] += red[tid + st]; __syncthreads(); }
    const float inv = rsqrtf(red[0] * (1.0f / 1024.0f) + 1e-5f);

    #pragma unroll
    for (int j = 0; j < 4; ++j) {
        const int c = tid + j * 256;
        out[(size_t)row * C_DIM + c] = (v[j] - mean) * inv * gw[c] + bw[c];
    }
}

// ---------------------------------------------------------------------------
// GEMM: out[M,N] = act(A[M,K] @ W[K,N] + bias[N]) (+ resid[M,N]).
// All f32. 64x64 tile, 16-wide K panels, 4x4 micro-tile.
// act: 0 = none, 1 = exact gelu.
// ---------------------------------------------------------------------------
__global__ __launch_bounds__(256) void gemm_kernel(
    const float* __restrict__ A, const float* __restrict__ W,
    const float* __restrict__ bias, const float* __restrict__ resid,
    float* __restrict__ out, int M, int N, int K, int act)
{
    __shared__ float As[16][65];
    __shared__ float Bs[16][64];

    const int tid = threadIdx.x;
    const int tx = tid & 15, ty = tid >> 4;
    const int row0 = blockIdx.y * 64, col0 = blockIdx.x * 64;

    float acc[4][4] = {};

    for (int k0 = 0; k0 < K; k0 += 16) {
        #pragma unroll
        for (int j = 0; j < 4; ++j) {
            int e = tid + j * 256;
            int r = e >> 4, kk = e & 15;
            As[kk][r] = A[(size_t)(row0 + r) * K + k0 + kk];
        }
        #pragma unroll
        for (int j = 0; j < 4; ++j) {
            int e = tid + j * 256;
            int kk = e >> 6, c = e & 63;
            Bs[kk][c] = W[(size_t)(k0 + kk) * N + col0 + c];
        }
        __syncthreads();
        #pragma unroll
        for (int kk = 0; kk < 16; ++kk) {
            float a0 = As[kk][ty], a1 = As[kk][ty + 16], a2 = As[kk][ty + 32], a3 = As[kk][ty + 48];
            float b0 = Bs[kk][tx], b1 = Bs[kk][tx + 16], b2 = Bs[kk][tx + 32], b3 = Bs[kk][tx + 48];
            acc[0][0] += a0 * b0; acc[0][1] += a0 * b1; acc[0][2] += a0 * b2; acc[0][3] += a0 * b3;
            acc[1][0] += a1 * b0; acc[1][1] += a1 * b1; acc[1][2] += a1 * b2; acc[1][3] += a1 * b3;
            acc[2][0] += a2 * b0; acc[2][1] += a2 * b1; acc[2][2] += a2 * b2; acc[2][3] += a2 * b3;
            acc[3][0] += a3 * b0; acc[3][1] += a3 * b1; acc[3][2] += a3 * b2; acc[3][3] += a3 * b3;
        }
        __syncthreads();
    }

    #pragma unroll
    for (int ri = 0; ri < 4; ++ri) {
        const int row = row0 + ty + 16 * ri;
        #pragma unroll
        for (int ci = 0; ci < 4; ++ci) {
            const int col = col0 + tx + 16 * ci;
            float v = acc[ri][ci] + bias[col];
            if (act == 1) v = 0.5f * v * (1.0f + erff(v * 0.70710678118f));
            if (resid) v += resid[(size_t)row * N + col];
            out[(size_t)row * N + col] = v;
        }
    }
}

// ---------------------------------------------------------------------------
// Attention: one block per (q, h, b). Q,K,V in plain (B*S, C) layout,
// head h occupies cols [h*64, h*64+64). Causal mask, softmax, PV.
// ---------------------------------------------------------------------------
__global__ __launch_bounds__(256) void attn_kernel(
    const float* __restrict__ Q, const float* __restrict__ Kb,
    const float* __restrict__ Vb, float* __restrict__ Y)
{
    const int qi = blockIdx.x, h = blockIdx.y, b = blockIdx.z;
    const int tid = threadIdx.x;

    __shared__ float qv[64];
    __shared__ float sc[S_LEN];
    __shared__ float red[256];
    __shared__ float part[4][64];

    const size_t base = (size_t)b * S_LEN * C_DIM + (size_t)h * HDIM;

    if (tid < 64) qv[tid] = Q[base + (size_t)qi * C_DIM + tid];
    __syncthreads();

    // scores + running max
    float lmax = -1e30f;
    #pragma unroll
    for (int j = 0; j < 3; ++j) {
        const int kk = tid + j * 256;
        float s;
        if (kk <= qi) {
            const float* kr = Kb + base + (size_t)kk * C_DIM;
            float d = 0.f;
            #pragma unroll 8
            for (int c = 0; c < 64; ++c) d += qv[c] * kr[c];
            s = d * 0.125f;  // 1/sqrt(64)
        } else {
            s = -1e30f;
        }
        sc[kk] = s;
        lmax = fmaxf(lmax, s);
    }
    red[tid] = lmax; __syncthreads();
    for (int st = 128; st > 0; st >>= 1) { if (tid < st) red[tid] = fmaxf(red[tid], red[tid + st]); __syncthreads(); }
    const float m = red[0];
    __syncthreads();

    float lsum = 0.f;
    #pragma unroll
    for (int j = 0; j < 3; ++j) {
        const int kk = tid + j * 256;
        const float p = __expf(sc[kk] - m);   // masked -> exp(very negative) = 0
        sc[kk] = p;
        lsum += p;
    }
    red[tid] = lsum; __syncthreads();
    for (int st = 128; st > 0; st >>= 1) { if (tid < st) red[tid] += red[tid + st]; __syncthreads(); }
    const float inv = 1.0f / red[0];

    // y[d] = sum_k p[k] * V[k][d] ; thread (ch,d) does a 192-key chunk of dim d
    const int d = tid & 63, ch = tid >> 6;
    float accv = 0.f;
    const int kbeg = ch * 192, kend = kbeg + 192;
    for (int kk = kbeg; kk < kend; ++kk)
        accv += sc[kk] * Vb[base + (size_t)kk * C_DIM + d];
    part[ch][d] = accv;
    __syncthreads();

    if (tid < 64) {
        const float y = (part[0][tid] + part[1][tid] + part[2][tid] + part[3][tid]) * inv;
        Y[base + (size_t)qi * C_DIM + tid] = y;
    }
}

// ---------------------------------------------------------------------------
// Head: one block per (b,t); take final-LN row at s=3t+1, multiply by
// head_w (1024,80), write f32 logits.
// ---------------------------------------------------------------------------
__global__ __launch_bounds__(256) void head_kernel(
    const float* __restrict__ A, const float* __restrict__ hw,
    float* __restrict__ out)
{
    const int n = blockIdx.x;           // b*T + t
    const int b = n >> 8, t = n & 255;
    const int tid = threadIdx.x;
    __shared__ float rowv[C_DIM];

    const float* x = A + ((size_t)b * S_LEN + 3 * t + 1) * C_DIM;
    #pragma unroll
    for (int j = 0; j < 4; ++j) rowv[tid + j * 256] = x[tid + j * 256];
    __syncthreads();

    if (tid < NACT) {
        float a = 0.f;
        for (int k = 0; k < C_DIM; ++k) a += rowv[k] * hw[k * NACT + tid];
        out[(size_t)n * NACT + tid] = a;
    }
}

// ---------------------------------------------------------------------------
extern "C" void kernel_launch(void* const* d_in, const int* in_sizes, int n_in,
                              void* d_out, int out_size, void* d_ws, size_t ws_size,
                              hipStream_t stream) {
    const float* states  = (const float*)d_in[0];
    const float* rtgs    = (const float*)d_in[1];
    const float* meta    = (const float*)d_in[2];
    // d_in[3] circuit_feas: unused (zeroed in reference)
    const float* c1w = (const float*)d_in[4];
    const float* c1b = (const float*)d_in[5];
    const float* c2w = (const float*)d_in[6];
    const float* c2b = (const float*)d_in[7];
    const float* c3w = (const float*)d_in[8];
    const float* c3b = (const float*)d_in[9];
    const float* encw = (const float*)d_in[10];
    const float* encb = (const float*)d_in[11];
    const float* mw1 = (const float*)d_in[12];
    const float* mb1 = (const float*)d_in[13];
    const float* mw2 = (const float*)d_in[14];
    const float* mb2 = (const float*)d_in[15];
    const float* retw = (const float*)d_in[16];
    const float* retb = (const float*)d_in[17];
    const float* aemb = (const float*)d_in[18];
    const float* pos  = (const float*)d_in[19];
    const float* gpos = (const float*)d_in[20];
    const float* ln1g = (const float*)d_in[21];
    const float* ln1b = (const float*)d_in[22];
    const float* ln2g = (const float*)d_in[23];
    const float* ln2b = (const float*)d_in[24];
    const float* Wq = (const float*)d_in[25];
    const float* bq = (const float*)d_in[26];
    const float* Wk = (const float*)d_in[27];
    const float* bk = (const float*)d_in[28];
    const float* Wv = (const float*)d_in[29];
    const float* bv = (const float*)d_in[30];
    const float* Wo = (const float*)d_in[31];
    const float* bo = (const float*)d_in[32];
    const float* Wm1 = (const float*)d_in[33];
    const float* bm1 = (const float*)d_in[34];
    const float* Wm2 = (const float*)d_in[35];
    const float* bm2 = (const float*)d_in[36];
    const float* lnfg = (const float*)d_in[37];
    const float* lnfb = (const float*)d_in[38];
    const float* hw   = (const float*)d_in[39];
    const int* actions   = (const int*)d_in[40];
    const int* timesteps = (const int*)d_in[41];

    float* out = (float*)d_out;

    const size_t SLAB = (size_t)MROWS * C_DIM;   // 3072*1024 floats
    float* X  = (float*)d_ws;
    float* Ab = X + SLAB;
    float* S0 = Ab + SLAB;
    float* S1 = S0 + SLAB;
    float* S2 = S1 + SLAB;
    // S0..S3 contiguous: MLP hidden (3072 x 4096) occupies S0 onward (4 slabs).

    // 1) embeddings -> X
    embed_kernel<<<BATCH * TCTX, 256, 0, stream>>>(
        states, rtgs, meta, c1w, c1b, c2w, c2b, c3w, c3b, encw, encb,
        mw1, mb1, mw2, mb2, retw, retb, aemb, pos, gpos, actions, timesteps, X);

    const dim3 g1024(C_DIM / 64, MROWS / 64);   // (16, 48)
    const dim3 g4096(DFF / 64, MROWS / 64);     // (64, 48)
    const dim3 gattn(S_LEN, NHEAD, BATCH);

    for (int i = 0; i < 6; ++i) {
        const size_t wOff = (size_t)i * C_DIM * C_DIM;
        const size_t bOff = (size_t)i * C_DIM;
        const size_t m1Off = (size_t)i * C_DIM * DFF;

        // ln1 -> Ab
        ln_kernel<<<MROWS, 256, 0, stream>>>(X, Ab, ln1g + bOff, ln1b + bOff);
        // q,k,v
        gemm_kernel<<<g1024, 256, 0, stream>>>(Ab, Wq + wOff, bq + bOff, nullptr, S0, MROWS, C_DIM, C_DIM, 0);
        gemm_kernel<<<g1024, 256, 0, stream>>>(Ab, Wk + wOff, bk + bOff, nullptr, S1, MROWS, C_DIM, C_DIM, 0);
        gemm_kernel<<<g1024, 256, 0, stream>>>(Ab, Wv + wOff, bv + bOff, nullptr, S2, MROWS, C_DIM, C_DIM, 0);
        // attention -> Ab (hx no longer needed)
        attn_kernel<<<gattn, 256, 0, stream>>>(S0, S1, S2, Ab);
        // out proj + residual -> X
        gemm_kernel<<<g1024, 256, 0, stream>>>(Ab, Wo + wOff, bo + bOff, X, X, MROWS, C_DIM, C_DIM, 0);
        // ln2 -> Ab
        ln_kernel<<<MROWS, 256, 0, stream>>>(X, Ab, ln2g + bOff, ln2b + bOff);
        // mlp up + gelu -> S0 (spans 4 slabs)
        gemm_kernel<<<g4096, 256, 0, stream>>>(Ab, Wm1 + m1Off, bm1 + (size_t)i * DFF, nullptr, S0, MROWS, DFF, C_DIM, 1);
        // mlp down + residual -> X
        gemm_kernel<<<g1024, 256, 0, stream>>>(S0, Wm2 + m1Off, bm2 + bOff, X, X, MROWS, C_DIM, DFF, 0);
    }

    // final LN -> Ab, head -> out
    ln_kernel<<<MROWS, 256, 0, stream>>>(X, Ab, lnfg, lnfb);
    head_kernel<<<BATCH * TCTX, 256, 0, stream>>>(Ab, hw, out);
}

// Round 3
// 4384.885 us; speedup vs baseline: 3.2702x; 3.2702x over previous
//
#include <hip/hip_runtime.h>
#include <hip/hip_bf16.h>

// ---------------------------------------------------------------------------
// Decision-Transformer forward, MI355X round 3:
//  - GEMMs -> MFMA bf16 (16x16x32), 128x128 tiles, BK=32, f32 accum.
//    Activations produced directly in bf16; f32 weights converted in staging.
//  - Attention -> flash-style tiled online-softmax (f32 VALU), 64-q tiles.
// L=6, H=16, C=1024, T=256, S=3T=768, B=4, D_FF=4096, NACT=80.
// ---------------------------------------------------------------------------

#define S_LEN 768
#define C_DIM 1024
#define NHEAD 16
#define HDIM 64
#define BATCH 4
#define TCTX 256
#define DFF 4096
#define NACT 80
#define MROWS (BATCH * S_LEN)   // 3072

typedef __attribute__((ext_vector_type(4))) float f32x4;
typedef __attribute__((ext_vector_type(8))) short bf16x8;

static __device__ __forceinline__ unsigned short f2bf(float f) {
    unsigned int u = __float_as_uint(f);
    u += 0x7FFF + ((u >> 16) & 1);          // RNE
    return (unsigned short)(u >> 16);
}
static __device__ __forceinline__ float bf2f(unsigned short h) {
    return __uint_as_float(((unsigned int)h) << 16);
}

// ---------------------------------------------------------------------------
// Embedding (unchanged from round 2): one block per (b,t) -> X f32.
// ---------------------------------------------------------------------------
__global__ __launch_bounds__(256) void embed_kernel(
    const float* __restrict__ states, const float* __restrict__ rtgs,
    const float* __restrict__ meta,
    const float* __restrict__ c1w, const float* __restrict__ c1b,
    const float* __restrict__ c2w, const float* __restrict__ c2b,
    const float* __restrict__ c3w, const float* __restrict__ c3b,
    const float* __restrict__ encw, const float* __restrict__ encb,
    const float* __restrict__ mw1, const float* __restrict__ mb1,
    const float* __restrict__ mw2, const float* __restrict__ mb2,
    const float* __restrict__ retw, const float* __restrict__ retb,
    const float* __restrict__ aemb, const float* __restrict__ pos,
    const float* __restrict__ gpos,
    const int* __restrict__ actions, const int* __restrict__ timesteps,
    float* __restrict__ X)
{
    const int n = blockIdx.x;          // b*T + t
    const int b = n >> 8, t = n & 255;
    const int tid = threadIdx.x;

    __shared__ float sin_[640];
    __shared__ float h1[96];
    __shared__ float h2[32];
    __shared__ float feat[16];
    __shared__ float hidm[32];
    __shared__ float mer[4];

    for (int e = tid; e < 640; e += 256)
        sin_[e] = states[(size_t)n * 640 + e];
    __syncthreads();

    if (tid < 96) {
        int o = tid / 6, rem = tid % 6, oh = rem / 3, ow = rem % 3;
        float a = c1b[o];
        for (int ci = 0; ci < 8; ++ci)
            for (int kh = 0; kh < 8; ++kh) {
                int ih = oh * 2 - 1 + kh;
                if (ih < 0 || ih >= 8) continue;
                for (int kw = 0; kw < 8; ++kw) {
                    int iw = ow * 2 - 1 + kw;
                    if (iw < 0 || iw >= 10) continue;
                    a += c1w[((o * 8 + ci) * 8 + kh) * 8 + kw] * sin_[ci * 80 + ih * 10 + iw];
                }
            }
        h1[tid] = fmaxf(a, 0.f);
    }
    if (tid < 32) {
        float a = mb1[tid];
        for (int i = 0; i < 4; ++i)
            a += meta[(size_t)n * 4 + i] * mw1[i * 32 + tid];
        hidm[tid] = fmaxf(a, 0.f);
    }
    __syncthreads();

    if (tid < 32) {
        float a = c2b[tid];
        for (int ci = 0; ci < 16; ++ci)
            for (int kh = 0; kh < 4; ++kh) {
                int ih = -1 + kh;
                if (ih < 0 || ih >= 2) continue;
                for (int kw = 0; kw < 4; ++kw) {
                    int iw = -1 + kw;
                    if (iw < 0 || iw >= 3) continue;
                    a += c2w[((tid * 16 + ci) * 4 + kh) * 4 + kw] * h1[ci * 6 + ih * 3 + iw];
                }
            }
        h2[tid] = fmaxf(a, 0.f);
    }
    __syncthreads();

    if (tid < 16) {
        float a = c3b[tid];
        for (int ci = 0; ci < 32; ++ci)
            a += c3w[(tid * 32 + ci) * 9 + 4] * h2[ci];
        feat[tid] = fmaxf(a, 0.f);
    }
    if (tid < 4) {
        float a = mb2[tid];
        for (int j = 0; j < 32; ++j) a += hidm[j] * mw2[j * 4 + tid];
        mer[tid] = a;
    }
    __syncthreads();

    const float r = rtgs[n];
    const int a_idx = actions[n];
    const int g = timesteps[b];
    const size_t xbase = ((size_t)b * S_LEN + 3 * t) * C_DIM;

    for (int c = tid; c < C_DIM; c += 256) {
        float se;
        if (c < 1020) {
            float acc = encb[c];
            #pragma unroll
            for (int k = 0; k < 16; ++k) acc += feat[k] * encw[k * 1020 + c];
            se = acc;
        } else {
            se = mer[c - 1020];
        }
        const float st = tanhf(se);
        const float rt = tanhf(r * retw[c] + retb[c]);
        const float ae = aemb[(size_t)a_idx * C_DIM + c];
        const float gp = gpos[(size_t)g * C_DIM + c];
        X[xbase + c]             = rt + gp + pos[(size_t)(3 * t + 0) * C_DIM + c];
        X[xbase + C_DIM + c]     = st + gp + pos[(size_t)(3 * t + 1) * C_DIM + c];
        X[xbase + 2 * C_DIM + c] = ae + gp + pos[(size_t)(3 * t + 2) * C_DIM + c];
    }
}

// ---------------------------------------------------------------------------
// LayerNorm over last dim (1024), bf16 output (GEMM A-input).
// ---------------------------------------------------------------------------
__global__ __launch_bounds__(256) void ln_bf16_kernel(
    const float* __restrict__ in, unsigned short* __restrict__ out,
    const float* __restrict__ gw, const float* __restrict__ bw)
{
    const int row = blockIdx.x, tid = threadIdx.x;
    __shared__ float red[256];
    const float* x = in + (size_t)row * C_DIM;

    float v[4];
    float s = 0.f;
    #pragma unroll
    for (int j = 0; j < 4; ++j) { v[j] = x[tid + j * 256]; s += v[j]; }
    red[tid] = s; __syncthreads();
    for (int st = 128; st > 0; st >>= 1) { if (tid < st) red[tid] += red[tid + st]; __syncthreads(); }
    const float mean = red[0] * (1.0f / 1024.0f);
    __syncthreads();

    float s2 = 0.f;
    #pragma unroll
    for (int j = 0; j < 4; ++j) { float d = v[j] - mean; s2 += d * d; }
    red[tid] = s2; __syncthreads();
    for (int st = 128; st > 0; st >>= 1) { if (tid < st) red[tid] += red[tid + st]; __syncthreads(); }
    const float inv = rsqrtf(red[0] * (1.0f / 1024.0f) + 1e-5f);

    #pragma unroll
    for (int j = 0; j < 4; ++j) {
        const int c = tid + j * 256;
        out[(size_t)row * C_DIM + c] = f2bf((v[j] - mean) * inv * gw[c] + bw[c]);
    }
}

// ---------------------------------------------------------------------------
// MFMA GEMM core: acc[4][4] per wave (64x64), block = 4 waves = 128x128 tile.
// A bf16 [M][K] row-major; W f32 [K][N] converted to bf16 in staging.
// LDS layout: [kgroup(4)][row-or-col(128)][8 bf16] -> conflict-free b128.
// ---------------------------------------------------------------------------
__device__ __forceinline__ void gemm_core(
    const unsigned short* __restrict__ A, const float* __restrict__ W,
    int row0, int col0, int N, int K, f32x4 (&acc)[4][4])
{
    __shared__ __align__(16) unsigned short As2[4][128][8];
    __shared__ __align__(16) unsigned short Bs2[4][128][8];

    const int tid = threadIdx.x;
    const int ar  = tid & 63, akg = tid >> 6;     // A staging: row, k-group
    const int bc  = tid & 127, bh = tid >> 7;     // B staging: col, k-half
    const int lane = tid & 63, w = tid >> 6;
    const int rwl = (w >> 1) * 64, cwl = (w & 1) * 64;
    const int mi = lane & 15, kg = lane >> 4;

    for (int k0 = 0; k0 < K; k0 += 32) {
        // global loads first (overlap with address calc)
        const unsigned short* pa = A + (size_t)(row0 + ar) * K + (k0 + akg * 8);
        uint4 va0 = *(const uint4*)pa;
        uint4 va1 = *(const uint4*)(pa + (size_t)64 * K);
        const float* pw = W + (size_t)(k0 + bh * 16) * N + (col0 + bc);
        unsigned short hb[16];
        #pragma unroll
        for (int i = 0; i < 16; ++i) hb[i] = f2bf(pw[(size_t)i * N]);

        *(uint4*)&As2[akg][ar][0]        = va0;
        *(uint4*)&As2[akg][ar + 64][0]   = va1;
        *(uint4*)&Bs2[bh * 2][bc][0]     = *(uint4*)&hb[0];
        *(uint4*)&Bs2[bh * 2 + 1][bc][0] = *(uint4*)&hb[8];
        __syncthreads();

        bf16x8 af[4], bfr[4];
        #pragma unroll
        for (int i = 0; i < 4; ++i) {
            af[i]  = *(const bf16x8*)&As2[kg][rwl + i * 16 + mi][0];
            bfr[i] = *(const bf16x8*)&Bs2[kg][cwl + i * 16 + mi][0];
        }
        #pragma unroll
        for (int ri = 0; ri < 4; ++ri)
            #pragma unroll
            for (int ci = 0; ci < 4; ++ci)
                acc[ri][ci] = __builtin_amdgcn_mfma_f32_16x16x32_bf16(
                    af[ri], bfr[ci], acc[ri][ci], 0, 0, 0);
        __syncthreads();
    }
}

// Generic epilogue variants. ACT: 1=gelu. OUTB: 1=bf16 out. RES: add resid.
template<int ACT, int OUTB, int RES>
__global__ __launch_bounds__(256) void mfma_gemm(
    const unsigned short* __restrict__ A, const float* __restrict__ W,
    const float* __restrict__ bias, const float* resid,
    float* outf, unsigned short* __restrict__ outb,
    int N, int K)
{
    const int row0 = blockIdx.y * 128, col0 = blockIdx.x * 128;
    f32x4 acc[4][4] = {};
    gemm_core(A, W, row0, col0, N, K, acc);

    const int lane = threadIdx.x & 63, w = threadIdx.x >> 6;
    const int rwl = (w >> 1) * 64, cwl = (w & 1) * 64;
    const int mi = lane & 15, kg = lane >> 4;

    #pragma unroll
    for (int ri = 0; ri < 4; ++ri) {
        #pragma unroll
        for (int ci = 0; ci < 4; ++ci) {
            #pragma unroll
            for (int j = 0; j < 4; ++j) {
                const int row = row0 + rwl + ri * 16 + kg * 4 + j;
                const int col = col0 + cwl + ci * 16 + mi;
                float v = acc[ri][ci][j] + bias[col];
                if (ACT) v = 0.5f * v * (1.0f + erff(v * 0.70710678118f));
                if (RES) v += resid[(size_t)row * N + col];
                if (OUTB) outb[(size_t)row * N + col] = f2bf(v);
                else      outf[(size_t)row * N + col] = v;
            }
        }
    }
}

// QKV fused: blockIdx.x = group(3) * 8 + coltile; outputs to 3 contiguous slabs.
__global__ __launch_bounds__(256) void mfma_gemm_qkv(
    const unsigned short* __restrict__ A,
    const float* __restrict__ Wq, const float* __restrict__ Wk, const float* __restrict__ Wv,
    const float* __restrict__ bq, const float* __restrict__ bk, const float* __restrict__ bv,
    float* __restrict__ out0)
{
    const int grp = blockIdx.x >> 3;
    const float* W    = grp == 0 ? Wq : (grp == 1 ? Wk : Wv);
    const float* bias = grp == 0 ? bq : (grp == 1 ? bk : bv);
    float* outf = out0 + (size_t)grp * ((size_t)MROWS * C_DIM);
    const int row0 = blockIdx.y * 128, col0 = (blockIdx.x & 7) * 128;

    f32x4 acc[4][4] = {};
    gemm_core(A, W, row0, col0, C_DIM, C_DIM, acc);

    const int lane = threadIdx.x & 63, w = threadIdx.x >> 6;
    const int rwl = (w >> 1) * 64, cwl = (w & 1) * 64;
    const int mi = lane & 15, kg = lane >> 4;

    #pragma unroll
    for (int ri = 0; ri < 4; ++ri) {
        #pragma unroll
        for (int ci = 0; ci < 4; ++ci) {
            #pragma unroll
            for (int j = 0; j < 4; ++j) {
                const int row = row0 + rwl + ri * 16 + kg * 4 + j;
                const int col = col0 + cwl + ci * 16 + mi;
                outf[(size_t)row * C_DIM + col] = acc[ri][ci][j] + bias[col];
            }
        }
    }
}

// ---------------------------------------------------------------------------
// Flash attention: block per (qtile=64, h, b). f32 VALU, online softmax.
// Q,K,V f32 (B*S, C) head-strided; output Yb bf16.
// ---------------------------------------------------------------------------
__global__ __launch_bounds__(256) void attn_flash(
    const float* __restrict__ Q, const float* __restrict__ Kg,
    const float* __restrict__ Vg, unsigned short* __restrict__ Yb)
{
    const int qt = blockIdx.x, h = blockIdx.y, b = blockIdx.z;
    const int tid = threadIdx.x;
    const int q0 = qt * 64;

    __shared__ float Qs[64][68];
    __shared__ float Kt[64][68];
    __shared__ float Vt[64][68];
    __shared__ float Pt[64 * 67 + 4];
    __shared__ float m_s[64], l_s[64], al_s[64];
    __shared__ float rmax[64][4], rsum[64][4];

    const size_t base = (size_t)b * S_LEN * C_DIM + (size_t)h * HDIM;

    {   // load Q tile
        const int r = tid >> 2, p = tid & 3;
        const float* src = Q + base + (size_t)(q0 + r) * C_DIM + p * 16;
        #pragma unroll
        for (int i = 0; i < 4; ++i)
            *(float4*)&Qs[r][p * 16 + i * 4] = *(const float4*)(src + i * 4);
    }
    if (tid < 64) { m_s[tid] = -1e30f; l_s[tid] = 0.f; }

    float O[16];
    #pragma unroll
    for (int j = 0; j < 16; ++j) O[j] = 0.f;

    const int qa = tid >> 2, kq = tid & 3;    // score phase: q-row, k-subset
    const int oq = tid & 63, dg = tid >> 6;   // O phase: q-row, d-group

    for (int kt = 0; kt <= qt; ++kt) {
        __syncthreads();   // previous iteration's readers done before restage
        {   // stage K/V tiles
            const int r = tid >> 2, p = tid & 3;
            const float* sk = Kg + base + (size_t)(kt * 64 + r) * C_DIM + p * 16;
            const float* sv = Vg + base + (size_t)(kt * 64 + r) * C_DIM + p * 16;
            #pragma unroll
            for (int i = 0; i < 4; ++i) {
                *(float4*)&Kt[r][p * 16 + i * 4] = *(const float4*)(sk + i * 4);
                *(float4*)&Vt[r][p * 16 + i * 4] = *(const float4*)(sv + i * 4);
            }
        }
        __syncthreads();

        // scores: thread covers k = kq + 4*i  (stride-4 avoids bank clash)
        const bool last = (kt == qt);
        float sc[16];
        float lmax = -1e30f;
        #pragma unroll
        for (int i = 0; i < 16; ++i) {
            const int k = kq + 4 * i;
            float d = 0.f;
            #pragma unroll 8
            for (int c = 0; c < 64; ++c) d += Qs[qa][c] * Kt[k][c];
            d *= 0.125f;
            if (last && k > qa) d = -1e30f;
            sc[i] = d;
            lmax = fmaxf(lmax, d);
        }
        rmax[qa][kq] = lmax;
        __syncthreads();
        if (tid < 64) {
            const float mo = m_s[tid];
            float mn = fmaxf(fmaxf(rmax[tid][0], rmax[tid][1]),
                             fmaxf(rmax[tid][2], rmax[tid][3]));
            mn = fmaxf(mo, mn);
            al_s[tid] = __expf(mo - mn);
            m_s[tid] = mn;
        }
        __syncthreads();

        {   // P = exp(S - m), partial row sums
            const float mn = m_s[qa];
            float lsum = 0.f;
            #pragma unroll
            for (int i = 0; i < 16; ++i) {
                const float p = __expf(sc[i] - mn);
                Pt[qa * 67 + kq + 4 * i] = p;
                lsum += p;
            }
            rsum[qa][kq] = lsum;
        }
        __syncthreads();
        if (tid < 64)
            l_s[tid] = l_s[tid] * al_s[tid] +
                       rsum[tid][0] + rsum[tid][1] + rsum[tid][2] + rsum[tid][3];

        {   // O = O*alpha + P @ Vt
            const float al = al_s[oq];
            #pragma unroll
            for (int j = 0; j < 16; ++j) O[j] *= al;
            for (int k = 0; k < 64; ++k) {
                const float p = Pt[oq * 67 + k];
                #pragma unroll
                for (int j = 0; j < 16; ++j)
                    O[j] += p * Vt[k][dg * 16 + j];
            }
        }
    }
    __syncthreads();
    {
        const float inv = 1.0f / l_s[oq];
        unsigned short* dst = Yb + base + (size_t)(q0 + oq) * C_DIM + dg * 16;
        #pragma unroll
        for (int j = 0; j < 16; ++j) dst[j] = f2bf(O[j] * inv);
    }
}

// ---------------------------------------------------------------------------
// Head: block per (b,t); bf16 final-LN row @ s=3t+1 times head_w -> f32 out.
// ---------------------------------------------------------------------------
__global__ __launch_bounds__(256) void head_kernel(
    const unsigned short* __restrict__ Xb, const float* __restrict__ hw,
    float* __restrict__ out)
{
    const int n = blockIdx.x;           // b*T + t
    const int b = n >> 8, t = n & 255;
    const int tid = threadIdx.x;
    __shared__ float rowv[C_DIM];

    const unsigned short* x = Xb + ((size_t)b * S_LEN + 3 * t + 1) * C_DIM;
    #pragma unroll
    for (int j = 0; j < 4; ++j) rowv[tid + j * 256] = bf2f(x[tid + j * 256]);
    __syncthreads();

    if (tid < NACT) {
        float a = 0.f;
        for (int k = 0; k < C_DIM; ++k) a += rowv[k] * hw[k * NACT + tid];
        out[(size_t)n * NACT + tid] = a;
    }
}

// ---------------------------------------------------------------------------
extern "C" void kernel_launch(void* const* d_in, const int* in_sizes, int n_in,
                              void* d_out, int out_size, void* d_ws, size_t ws_size,
                              hipStream_t stream) {
    const float* states  = (const float*)d_in[0];
    const float* rtgs    = (const float*)d_in[1];
    const float* meta    = (const float*)d_in[2];
    const float* c1w = (const float*)d_in[4];
    const float* c1b = (const float*)d_in[5];
    const float* c2w = (const float*)d_in[6];
    const float* c2b = (const float*)d_in[7];
    const float* c3w = (const float*)d_in[8];
    const float* c3b = (const float*)d_in[9];
    const float* encw = (const float*)d_in[10];
    const float* encb = (const float*)d_in[11];
    const float* mw1 = (const float*)d_in[12];
    const float* mb1 = (const float*)d_in[13];
    const float* mw2 = (const float*)d_in[14];
    const float* mb2 = (const float*)d_in[15];
    const float* retw = (const float*)d_in[16];
    const float* retb = (const float*)d_in[17];
    const float* aemb = (const float*)d_in[18];
    const float* pos  = (const float*)d_in[19];
    const float* gpos = (const float*)d_in[20];
    const float* ln1g = (const float*)d_in[21];
    const float* ln1b = (const float*)d_in[22];
    const float* ln2g = (const float*)d_in[23];
    const float* ln2b = (const float*)d_in[24];
    const float* Wq = (const float*)d_in[25];
    const float* bq = (const float*)d_in[26];
    const float* Wk = (const float*)d_in[27];
    const float* bk = (const float*)d_in[28];
    const float* Wv = (const float*)d_in[29];
    const float* bv = (const float*)d_in[30];
    const float* Wo = (const float*)d_in[31];
    const float* bo = (const float*)d_in[32];
    const float* Wm1 = (const float*)d_in[33];
    const float* bm1 = (const float*)d_in[34];
    const float* Wm2 = (const float*)d_in[35];
    const float* bm2 = (const float*)d_in[36];
    const float* lnfg = (const float*)d_in[37];
    const float* lnfb = (const float*)d_in[38];
    const float* hw   = (const float*)d_in[39];
    const int* actions   = (const int*)d_in[40];
    const int* timesteps = (const int*)d_in[41];

    float* out = (float*)d_out;

    // workspace layout (bytes): X[0,12M) S0[12,24) S1[24,36) S2[36,48)
    //                           Xb[48,54) Yb[54,60)   (Hb overlaps S0..S2)
    char* wsc = (char*)d_ws;
    const size_t SLABB = (size_t)MROWS * C_DIM * 4;   // 12 MB
    float* X  = (float*)wsc;
    float* S0 = (float*)(wsc + SLABB);
    float* S1 = (float*)(wsc + 2 * SLABB);
    float* S2 = (float*)(wsc + 3 * SLABB);
    unsigned short* Hb = (unsigned short*)S0;                 // 3072x4096 bf16 = 24 MB
    unsigned short* Xb = (unsigned short*)(wsc + 4 * SLABB);  // 6 MB
    unsigned short* Yb = (unsigned short*)(wsc + 4 * SLABB + SLABB / 2);

    embed_kernel<<<BATCH * TCTX, 256, 0, stream>>>(
        states, rtgs, meta, c1w, c1b, c2w, c2b, c3w, c3b, encw, encb,
        mw1, mb1, mw2, mb2, retw, retb, aemb, pos, gpos, actions, timesteps, X);

    const dim3 gqkv(24, 24);       // 3 groups x 8 col-tiles, 24 row-tiles
    const dim3 g1024(8, 24);
    const dim3 g4096(32, 24);
    const dim3 gattn(12, NHEAD, BATCH);

    for (int i = 0; i < 6; ++i) {
        const size_t wOff = (size_t)i * C_DIM * C_DIM;
        const size_t bOff = (size_t)i * C_DIM;
        const size_t m1Off = (size_t)i * C_DIM * DFF;

        ln_bf16_kernel<<<MROWS, 256, 0, stream>>>(X, Xb, ln1g + bOff, ln1b + bOff);
        mfma_gemm_qkv<<<gqkv, 256, 0, stream>>>(
            Xb, Wq + wOff, Wk + wOff, Wv + wOff, bq + bOff, bk + bOff, bv + bOff, S0);
        attn_flash<<<gattn, 256, 0, stream>>>(S0, S1, S2, Yb);
        mfma_gemm<0, 0, 1><<<g1024, 256, 0, stream>>>(
            Yb, Wo + wOff, bo + bOff, X, X, nullptr, C_DIM, C_DIM);
        ln_bf16_kernel<<<MROWS, 256, 0, stream>>>(X, Xb, ln2g + bOff, ln2b + bOff);
        mfma_gemm<1, 1, 0><<<g4096, 256, 0, stream>>>(
            Xb, Wm1 + m1Off, bm1 + (size_t)i * DFF, nullptr, nullptr, Hb, DFF, C_DIM);
        mfma_gemm<0, 0, 1><<<g1024, 256, 0, stream>>>(
            Hb, Wm2 + m1Off, bm2 + bOff, X, X, nullptr, C_DIM, DFF);
    }

    ln_bf16_kernel<<<MROWS, 256, 0, stream>>>(X, Xb, lnfg, lnfb);
    head_kernel<<<BATCH * TCTX, 256, 0, stream>>>(Xb, hw, out);
}

// Round 4
// 3405.066 us; speedup vs baseline: 4.2112x; 1.2878x over previous
//
#include <hip/hip_runtime.h>
#include <hip/hip_bf16.h>

// ---------------------------------------------------------------------------
// Decision-Transformer forward, MI355X round 4:
//  - Per-layer weight f32->bf16 TRANSPOSED pre-conversion (Wb scratch, 24 MB):
//    GEMM B-staging becomes pure uint4 copies (no f2bf, half the bytes).
//  - Attention rewritten register-tiled: c-major Q/K tiles -> both score
//    operands are b128 vector LDS reads; softmax stats in registers;
//    row reductions via shfl_xor(width 16); PV reads P/V as b128.
// Workspace: 84 MB (X 12 | S0..S2 36 | Xb 6 | Yb 6 | Wb 24).
// ---------------------------------------------------------------------------

#define S_LEN 768
#define C_DIM 1024
#define NHEAD 16
#define HDIM 64
#define BATCH 4
#define TCTX 256
#define DFF 4096
#define NACT 80
#define MROWS (BATCH * S_LEN)   // 3072

typedef __attribute__((ext_vector_type(4))) float f32x4;
typedef __attribute__((ext_vector_type(8))) short bf16x8;

static __device__ __forceinline__ unsigned short f2bf(float f) {
    unsigned int u = __float_as_uint(f);
    u += 0x7FFF + ((u >> 16) & 1);          // RNE
    return (unsigned short)(u >> 16);
}
static __device__ __forceinline__ float bf2f(unsigned short h) {
    return __uint_as_float(((unsigned int)h) << 16);
}

// ---------------------------------------------------------------------------
// Weight conversion: per layer, f32 [K][N] -> bf16 transposed [N][K] in Wb.
// Wb elem offsets: WqT 0, WkT 1M, WvT 2M, WoT 3M, Wm1T 4M (N=4096,K=1024),
// Wm2T 8M (N=1024,K=4096). 64x64 tiles via LDS, coalesced in and out.
// ---------------------------------------------------------------------------
__global__ __launch_bounds__(256) void transpose_w_kernel(
    const float* __restrict__ Wq, const float* __restrict__ Wk,
    const float* __restrict__ Wv, const float* __restrict__ Wo,
    const float* __restrict__ Wm1, const float* __restrict__ Wm2,
    unsigned short* __restrict__ Wb)
{
    const int t = blockIdx.x;
    const float* src; unsigned short* dst; int K, N, kt, nt;
    if (t < 1024) {
        const int m = t >> 8, tile = t & 255;
        src = (m == 0) ? Wq : (m == 1) ? Wk : (m == 2) ? Wv : Wo;
        dst = Wb + (size_t)m * 1048576;
        K = 1024; N = 1024; kt = tile >> 4; nt = tile & 15;
    } else if (t < 2048) {
        const int tile = t - 1024;
        src = Wm1; dst = Wb + (size_t)4 * 1048576;
        K = 1024; N = 4096; kt = tile >> 6; nt = tile & 63;
    } else {
        const int tile = t - 2048;
        src = Wm2; dst = Wb + (size_t)8 * 1048576;
        K = 4096; N = 1024; kt = tile >> 4; nt = tile & 15;
    }
    const int k0 = kt * 64, n0 = nt * 64;
    __shared__ float Ls[64][65];

    const int r = threadIdx.x >> 2, p = threadIdx.x & 3;
    #pragma unroll
    for (int i = 0; i < 4; ++i)
        *(float4*)&Ls[r][p * 16 + i * 4] =
            *(const float4*)&src[(size_t)(k0 + r) * N + n0 + p * 16 + i * 4];
    __syncthreads();

    unsigned short __align__(16) h[16];
    #pragma unroll
    for (int i = 0; i < 16; ++i) h[i] = f2bf(Ls[p * 16 + i][r]);
    unsigned short* d = dst + (size_t)(n0 + r) * K + k0 + p * 16;
    *(uint4*)d       = *(uint4*)&h[0];
    *(uint4*)(d + 8) = *(uint4*)&h[8];
}

// ---------------------------------------------------------------------------
// Embedding (unchanged): one block per (b,t) -> X f32.
// ---------------------------------------------------------------------------
__global__ __launch_bounds__(256) void embed_kernel(
    const float* __restrict__ states, const float* __restrict__ rtgs,
    const float* __restrict__ meta,
    const float* __restrict__ c1w, const float* __restrict__ c1b,
    const float* __restrict__ c2w, const float* __restrict__ c2b,
    const float* __restrict__ c3w, const float* __restrict__ c3b,
    const float* __restrict__ encw, const float* __restrict__ encb,
    const float* __restrict__ mw1, const float* __restrict__ mb1,
    const float* __restrict__ mw2, const float* __restrict__ mb2,
    const float* __restrict__ retw, const float* __restrict__ retb,
    const float* __restrict__ aemb, const float* __restrict__ pos,
    const float* __restrict__ gpos,
    const int* __restrict__ actions, const int* __restrict__ timesteps,
    float* __restrict__ X)
{
    const int n = blockIdx.x;
    const int b = n >> 8, t = n & 255;
    const int tid = threadIdx.x;

    __shared__ float sin_[640];
    __shared__ float h1[96];
    __shared__ float h2[32];
    __shared__ float feat[16];
    __shared__ float hidm[32];
    __shared__ float mer[4];

    for (int e = tid; e < 640; e += 256)
        sin_[e] = states[(size_t)n * 640 + e];
    __syncthreads();

    if (tid < 96) {
        int o = tid / 6, rem = tid % 6, oh = rem / 3, ow = rem % 3;
        float a = c1b[o];
        for (int ci = 0; ci < 8; ++ci)
            for (int kh = 0; kh < 8; ++kh) {
                int ih = oh * 2 - 1 + kh;
                if (ih < 0 || ih >= 8) continue;
                for (int kw = 0; kw < 8; ++kw) {
                    int iw = ow * 2 - 1 + kw;
                    if (iw < 0 || iw >= 10) continue;
                    a += c1w[((o * 8 + ci) * 8 + kh) * 8 + kw] * sin_[ci * 80 + ih * 10 + iw];
                }
            }
        h1[tid] = fmaxf(a, 0.f);
    }
    if (tid < 32) {
        float a = mb1[tid];
        for (int i = 0; i < 4; ++i)
            a += meta[(size_t)n * 4 + i] * mw1[i * 32 + tid];
        hidm[tid] = fmaxf(a, 0.f);
    }
    __syncthreads();

    if (tid < 32) {
        float a = c2b[tid];
        for (int ci = 0; ci < 16; ++ci)
            for (int kh = 0; kh < 4; ++kh) {
                int ih = -1 + kh;
                if (ih < 0 || ih >= 2) continue;
                for (int kw = 0; kw < 4; ++kw) {
                    int iw = -1 + kw;
                    if (iw < 0 || iw >= 3) continue;
                    a += c2w[((tid * 16 + ci) * 4 + kh) * 4 + kw] * h1[ci * 6 + ih * 3 + iw];
                }
            }
        h2[tid] = fmaxf(a, 0.f);
    }
    __syncthreads();

    if (tid < 16) {
        float a = c3b[tid];
        for (int ci = 0; ci < 32; ++ci)
            a += c3w[(tid * 32 + ci) * 9 + 4] * h2[ci];
        feat[tid] = fmaxf(a, 0.f);
    }
    if (tid < 4) {
        float a = mb2[tid];
        for (int j = 0; j < 32; ++j) a += hidm[j] * mw2[j * 4 + tid];
        mer[tid] = a;
    }
    __syncthreads();

    const float r = rtgs[n];
    const int a_idx = actions[n];
    const int g = timesteps[b];
    const size_t xbase = ((size_t)b * S_LEN + 3 * t) * C_DIM;

    for (int c = tid; c < C_DIM; c += 256) {
        float se;
        if (c < 1020) {
            float acc = encb[c];
            #pragma unroll
            for (int k = 0; k < 16; ++k) acc += feat[k] * encw[k * 1020 + c];
            se = acc;
        } else {
            se = mer[c - 1020];
        }
        const float st = tanhf(se);
        const float rt = tanhf(r * retw[c] + retb[c]);
        const float ae = aemb[(size_t)a_idx * C_DIM + c];
        const float gp = gpos[(size_t)g * C_DIM + c];
        X[xbase + c]             = rt + gp + pos[(size_t)(3 * t + 0) * C_DIM + c];
        X[xbase + C_DIM + c]     = st + gp + pos[(size_t)(3 * t + 1) * C_DIM + c];
        X[xbase + 2 * C_DIM + c] = ae + gp + pos[(size_t)(3 * t + 2) * C_DIM + c];
    }
}

// ---------------------------------------------------------------------------
// LayerNorm over last dim (1024), bf16 output.
// ---------------------------------------------------------------------------
__global__ __launch_bounds__(256) void ln_bf16_kernel(
    const float* __restrict__ in, unsigned short* __restrict__ out,
    const float* __restrict__ gw, const float* __restrict__ bw)
{
    const int row = blockIdx.x, tid = threadIdx.x;
    __shared__ float red[256];
    const float* x = in + (size_t)row * C_DIM;

    float v[4];
    float s = 0.f;
    #pragma unroll
    for (int j = 0; j < 4; ++j) { v[j] = x[tid + j * 256]; s += v[j]; }
    red[tid] = s; __syncthreads();
    for (int st = 128; st > 0; st >>= 1) { if (tid < st) red[tid] += red[tid + st]; __syncthreads(); }
    const float mean = red[0] * (1.0f / 1024.0f);
    __syncthreads();

    float s2 = 0.f;
    #pragma unroll
    for (int j = 0; j < 4; ++j) { float d = v[j] - mean; s2 += d * d; }
    red[tid] = s2; __syncthreads();
    for (int st = 128; st > 0; st >>= 1) { if (tid < st) red[tid] += red[tid + st]; __syncthreads(); }
    const float inv = rsqrtf(red[0] * (1.0f / 1024.0f) + 1e-5f);

    #pragma unroll
    for (int j = 0; j < 4; ++j) {
        const int c = tid + j * 256;
        out[(size_t)row * C_DIM + c] = f2bf((v[j] - mean) * inv * gw[c] + bw[c]);
    }
}

// ---------------------------------------------------------------------------
// MFMA GEMM core: A bf16 [M][K] row-major; Bt bf16 [N][K] (pre-transposed).
// 128x128 tile, BK=32, 4 waves, 4x4 16x16x32 frags each, f32 accum.
// ---------------------------------------------------------------------------
__device__ __forceinline__ void gemm_core(
    const unsigned short* __restrict__ A, const unsigned short* __restrict__ Bt,
    int row0, int col0, int K, f32x4 (&acc)[4][4])
{
    __shared__ __align__(16) unsigned short As2[4][128][8];
    __shared__ __align__(16) unsigned short Bs2[4][128][8];

    const int tid = threadIdx.x;
    const int ar  = tid & 63, akg = tid >> 6;     // staging: row/col, k-group
    const int lane = tid & 63, w = tid >> 6;
    const int rwl = (w >> 1) * 64, cwl = (w & 1) * 64;
    const int mi = lane & 15, kg = lane >> 4;

    for (int k0 = 0; k0 < K; k0 += 32) {
        const unsigned short* pa = A + (size_t)(row0 + ar) * K + (k0 + akg * 8);
        uint4 va0 = *(const uint4*)pa;
        uint4 va1 = *(const uint4*)(pa + (size_t)64 * K);
        const unsigned short* pb = Bt + (size_t)(col0 + ar) * K + (k0 + akg * 8);
        uint4 vb0 = *(const uint4*)pb;
        uint4 vb1 = *(const uint4*)(pb + (size_t)64 * K);

        *(uint4*)&As2[akg][ar][0]      = va0;
        *(uint4*)&As2[akg][ar + 64][0] = va1;
        *(uint4*)&Bs2[akg][ar][0]      = vb0;
        *(uint4*)&Bs2[akg][ar + 64][0] = vb1;
        __syncthreads();

        bf16x8 af[4], bfr[4];
        #pragma unroll
        for (int i = 0; i < 4; ++i) {
            af[i]  = *(const bf16x8*)&As2[kg][rwl + i * 16 + mi][0];
            bfr[i] = *(const bf16x8*)&Bs2[kg][cwl + i * 16 + mi][0];
        }
        #pragma unroll
        for (int ri = 0; ri < 4; ++ri)
            #pragma unroll
            for (int ci = 0; ci < 4; ++ci)
                acc[ri][ci] = __builtin_amdgcn_mfma_f32_16x16x32_bf16(
                    af[ri], bfr[ci], acc[ri][ci], 0, 0, 0);
        __syncthreads();
    }
}

// Epilogue variants. ACT: 1=gelu. OUTB: 1=bf16 out. RES: add resid.
template<int ACT, int OUTB, int RES>
__global__ __launch_bounds__(256) void mfma_gemm(
    const unsigned short* __restrict__ A, const unsigned short* __restrict__ Bt,
    const float* __restrict__ bias, const float* resid,
    float* outf, unsigned short* __restrict__ outb,
    int N, int K)
{
    const int row0 = blockIdx.y * 128, col0 = blockIdx.x * 128;
    f32x4 acc[4][4] = {};
    gemm_core(A, Bt, row0, col0, K, acc);

    const int lane = threadIdx.x & 63, w = threadIdx.x >> 6;
    const int rwl = (w >> 1) * 64, cwl = (w & 1) * 64;
    const int mi = lane & 15, kg = lane >> 4;

    #pragma unroll
    for (int ri = 0; ri < 4; ++ri) {
        #pragma unroll
        for (int ci = 0; ci < 4; ++ci) {
            #pragma unroll
            for (int j = 0; j < 4; ++j) {
                const int row = row0 + rwl + ri * 16 + kg * 4 + j;
                const int col = col0 + cwl + ci * 16 + mi;
                float v = acc[ri][ci][j] + bias[col];
                if (ACT) v = 0.5f * v * (1.0f + erff(v * 0.70710678118f));
                if (RES) v += resid[(size_t)row * N + col];
                if (OUTB) outb[(size_t)row * N + col] = f2bf(v);
                else      outf[(size_t)row * N + col] = v;
            }
        }
    }
}

// QKV fused: blockIdx.x = group(3)*8 + coltile; Wb holds WqT/WkT/WvT.
__global__ __launch_bounds__(256) void mfma_gemm_qkv(
    const unsigned short* __restrict__ A, const unsigned short* __restrict__ Wb,
    const float* __restrict__ bq, const float* __restrict__ bk, const float* __restrict__ bv,
    float* __restrict__ out0)
{
    const int grp = blockIdx.x >> 3;
    const unsigned short* Bt = Wb + (size_t)grp * 1048576;
    const float* bias = grp == 0 ? bq : (grp == 1 ? bk : bv);
    float* outf = out0 + (size_t)grp * ((size_t)MROWS * C_DIM);
    const int row0 = blockIdx.y * 128, col0 = (blockIdx.x & 7) * 128;

    f32x4 acc[4][4] = {};
    gemm_core(A, Bt, row0, col0, C_DIM, acc);

    const int lane = threadIdx.x & 63, w = threadIdx.x >> 6;
    const int rwl = (w >> 1) * 64, cwl = (w & 1) * 64;
    const int mi = lane & 15, kg = lane >> 4;

    #pragma unroll
    for (int ri = 0; ri < 4; ++ri) {
        #pragma unroll
        for (int ci = 0; ci < 4; ++ci) {
            #pragma unroll
            for (int j = 0; j < 4; ++j) {
                const int row = row0 + rwl + ri * 16 + kg * 4 + j;
                const int col = col0 + cwl + ci * 16 + mi;
                outf[(size_t)row * C_DIM + col] = acc[ri][ci][j] + bias[col];
            }
        }
    }
}

// ---------------------------------------------------------------------------
// Attention v2: block per (qtile=64, h, b). Register-tiled, online softmax.
// LDS: Qst/Ktt c-major (both score operands b128), Vt row-major, Pq row-major.
// Thread (sq=tid>>4, sk=tid&15) owns 4q x 4k scores and 4q x 4d of O.
// Rows 4sq+i are wave-local -> m/l/alpha live in registers; row reductions
// via shfl_xor(width 16).
// ---------------------------------------------------------------------------
__global__ __launch_bounds__(256) void attn_flash(
    const float* __restrict__ Q, const float* __restrict__ Kg,
    const float* __restrict__ Vg, unsigned short* __restrict__ Yb)
{
    const int qt = blockIdx.x, h = blockIdx.y, b = blockIdx.z;
    const int tid = threadIdx.x;
    const int q0 = qt * 64;

    __shared__ float Qst[64][68];   // [c][q], Q pre-scaled by 1/8
    __shared__ float Ktt[64][68];   // [c][k]
    __shared__ float Vt[64][68];    // [k][d]
    __shared__ float Pq[64][68];    // [q][k]

    const size_t base = (size_t)b * S_LEN * C_DIM + (size_t)h * HDIM;
    const int r = tid >> 2, p = tid & 3;

    {   // stage Q transposed + scaled
        const float* src = Q + base + (size_t)(q0 + r) * C_DIM + p * 16;
        #pragma unroll
        for (int i = 0; i < 16; ++i)
            Qst[p * 16 + i][r] = src[i] * 0.125f;
    }

    const int sq = tid >> 4, sk = tid & 15;
    float mrow[4], lrow[4], O[4][4];
    #pragma unroll
    for (int i = 0; i < 4; ++i) {
        mrow[i] = -1e30f; lrow[i] = 0.f;
        #pragma unroll
        for (int j = 0; j < 4; ++j) O[i][j] = 0.f;
    }

    for (int kt = 0; kt <= qt; ++kt) {
        __syncthreads();   // prev iteration's readers done
        {   // stage K transposed, V row-major
            const float* skr = Kg + base + (size_t)(kt * 64 + r) * C_DIM + p * 16;
            const float* svr = Vg + base + (size_t)(kt * 64 + r) * C_DIM + p * 16;
            #pragma unroll
            for (int i = 0; i < 16; ++i)
                Ktt[p * 16 + i][r] = skr[i];
            #pragma unroll
            for (int i = 0; i < 4; ++i)
                *(float4*)&Vt[r][p * 16 + i * 4] = *(const float4*)(svr + i * 4);
        }
        __syncthreads();

        // ---- scores: 4q x 4k per thread, c-vectorized b128 reads
        float sa[4][4] = {};
        #pragma unroll 4
        for (int c = 0; c < 64; ++c) {
            const float4 qv = *(const float4*)&Qst[c][4 * sq];
            const float4 kv = *(const float4*)&Ktt[c][4 * sk];
            sa[0][0] += qv.x * kv.x; sa[0][1] += qv.x * kv.y; sa[0][2] += qv.x * kv.z; sa[0][3] += qv.x * kv.w;
            sa[1][0] += qv.y * kv.x; sa[1][1] += qv.y * kv.y; sa[1][2] += qv.y * kv.z; sa[1][3] += qv.y * kv.w;
            sa[2][0] += qv.z * kv.x; sa[2][1] += qv.z * kv.y; sa[2][2] += qv.z * kv.z; sa[2][3] += qv.z * kv.w;
            sa[3][0] += qv.w * kv.x; sa[3][1] += qv.w * kv.y; sa[3][2] += qv.w * kv.z; sa[3][3] += qv.w * kv.w;
        }
        if (kt == qt) {   // causal mask within diagonal tile
            #pragma unroll
            for (int i = 0; i < 4; ++i)
                #pragma unroll
                for (int j = 0; j < 4; ++j)
                    if (4 * sk + j > 4 * sq + i) sa[i][j] = -1e30f;
        }

        // ---- online softmax: row stats in registers, reduce over sk lanes
        float al[4];
        #pragma unroll
        for (int i = 0; i < 4; ++i) {
            float rm = fmaxf(fmaxf(sa[i][0], sa[i][1]), fmaxf(sa[i][2], sa[i][3]));
            rm = fmaxf(rm, __shfl_xor(rm, 1, 16));
            rm = fmaxf(rm, __shfl_xor(rm, 2, 16));
            rm = fmaxf(rm, __shfl_xor(rm, 4, 16));
            rm = fmaxf(rm, __shfl_xor(rm, 8, 16));
            const float mn = fmaxf(mrow[i], rm);
            al[i] = __expf(mrow[i] - mn);
            mrow[i] = mn;

            float4 pv;
            pv.x = __expf(sa[i][0] - mn);
            pv.y = __expf(sa[i][1] - mn);
            pv.z = __expf(sa[i][2] - mn);
            pv.w = __expf(sa[i][3] - mn);
            *(float4*)&Pq[4 * sq + i][4 * sk] = pv;
            float rs = pv.x + pv.y + pv.z + pv.w;
            rs += __shfl_xor(rs, 1, 16);
            rs += __shfl_xor(rs, 2, 16);
            rs += __shfl_xor(rs, 4, 16);
            rs += __shfl_xor(rs, 8, 16);
            lrow[i] = lrow[i] * al[i] + rs;
        }
        __syncthreads();   // Pq visible

        // ---- O = O*alpha + P @ V  (4q x 4d per thread, d-cols 4*sk..)
        #pragma unroll
        for (int i = 0; i < 4; ++i) {
            O[i][0] *= al[i]; O[i][1] *= al[i]; O[i][2] *= al[i]; O[i][3] *= al[i];
        }
        #pragma unroll 2
        for (int k4 = 0; k4 < 16; ++k4) {
            float4 pr[4], vr[4];
            #pragma unroll
            for (int i = 0; i < 4; ++i) pr[i] = *(const float4*)&Pq[4 * sq + i][k4 * 4];
            #pragma unroll
            for (int m = 0; m < 4; ++m) vr[m] = *(const float4*)&Vt[k4 * 4 + m][4 * sk];
            #pragma unroll
            for (int i = 0; i < 4; ++i) {
                O[i][0] += pr[i].x * vr[0].x + pr[i].y * vr[1].x + pr[i].z * vr[2].x + pr[i].w * vr[3].x;
                O[i][1] += pr[i].x * vr[0].y + pr[i].y * vr[1].y + pr[i].z * vr[2].y + pr[i].w * vr[3].y;
                O[i][2] += pr[i].x * vr[0].z + pr[i].y * vr[1].z + pr[i].z * vr[2].z + pr[i].w * vr[3].z;
                O[i][3] += pr[i].x * vr[0].w + pr[i].y * vr[1].w + pr[i].z * vr[2].w + pr[i].w * vr[3].w;
            }
        }
    }

    // ---- write O / l as bf16
    #pragma unroll
    for (int i = 0; i < 4; ++i) {
        const float inv = 1.0f / lrow[i];
        ushort4 w4;
        w4.x = f2bf(O[i][0] * inv);
        w4.y = f2bf(O[i][1] * inv);
        w4.z = f2bf(O[i][2] * inv);
        w4.w = f2bf(O[i][3] * inv);
        *(ushort4*)(Yb + base + (size_t)(q0 + 4 * sq + i) * C_DIM + 4 * sk) = w4;
    }
}

// ---------------------------------------------------------------------------
// Head: block per (b,t); bf16 final-LN row @ s=3t+1 times head_w -> f32 out.
// ---------------------------------------------------------------------------
__global__ __launch_bounds__(256) void head_kernel(
    const unsigned short* __restrict__ Xb, const float* __restrict__ hw,
    float* __restrict__ out)
{
    const int n = blockIdx.x;
    const int b = n >> 8, t = n & 255;
    const int tid = threadIdx.x;
    __shared__ float rowv[C_DIM];

    const unsigned short* x = Xb + ((size_t)b * S_LEN + 3 * t + 1) * C_DIM;
    #pragma unroll
    for (int j = 0; j < 4; ++j) rowv[tid + j * 256] = bf2f(x[tid + j * 256]);
    __syncthreads();

    if (tid < NACT) {
        float a = 0.f;
        for (int k = 0; k < C_DIM; ++k) a += rowv[k] * hw[k * NACT + tid];
        out[(size_t)n * NACT + tid] = a;
    }
}

// ---------------------------------------------------------------------------
extern "C" void kernel_launch(void* const* d_in, const int* in_sizes, int n_in,
                              void* d_out, int out_size, void* d_ws, size_t ws_size,
                              hipStream_t stream) {
    const float* states  = (const float*)d_in[0];
    const float* rtgs    = (const float*)d_in[1];
    const float* meta    = (const float*)d_in[2];
    const float* c1w = (const float*)d_in[4];
    const float* c1b = (const float*)d_in[5];
    const float* c2w = (const float*)d_in[6];
    const float* c2b = (const float*)d_in[7];
    const float* c3w = (const float*)d_in[8];
    const float* c3b = (const float*)d_in[9];
    const float* encw = (const float*)d_in[10];
    const float* encb = (const float*)d_in[11];
    const float* mw1 = (const float*)d_in[12];
    const float* mb1 = (const float*)d_in[13];
    const float* mw2 = (const float*)d_in[14];
    const float* mb2 = (const float*)d_in[15];
    const float* retw = (const float*)d_in[16];
    const float* retb = (const float*)d_in[17];
    const float* aemb = (const float*)d_in[18];
    const float* pos  = (const float*)d_in[19];
    const float* gpos = (const float*)d_in[20];
    const float* ln1g = (const float*)d_in[21];
    const float* ln1b = (const float*)d_in[22];
    const float* ln2g = (const float*)d_in[23];
    const float* ln2b = (const float*)d_in[24];
    const float* Wq = (const float*)d_in[25];
    const float* bq = (const float*)d_in[26];
    const float* Wk = (const float*)d_in[27];
    const float* bk = (const float*)d_in[28];
    const float* Wv = (const float*)d_in[29];
    const float* bv = (const float*)d_in[30];
    const float* Wo = (const float*)d_in[31];
    const float* bo = (const float*)d_in[32];
    const float* Wm1 = (const float*)d_in[33];
    const float* bm1 = (const float*)d_in[34];
    const float* Wm2 = (const float*)d_in[35];
    const float* bm2 = (const float*)d_in[36];
    const float* lnfg = (const float*)d_in[37];
    const float* lnfb = (const float*)d_in[38];
    const float* hw   = (const float*)d_in[39];
    const int* actions   = (const int*)d_in[40];
    const int* timesteps = (const int*)d_in[41];

    float* out = (float*)d_out;

    // ws layout (bytes): X[0,12M) S0[12,24) S1[24,36) S2[36,48)
    //                    Xb[48,54) Yb[54,60) Wb[60,84)
    // Hb (MLP hidden bf16, 24 MB) overlaps S0/S1 (dead during MLP phase).
    char* wsc = (char*)d_ws;
    const size_t SLABB = (size_t)MROWS * C_DIM * 4;   // 12 MB
    float* X  = (float*)wsc;
    float* S0 = (float*)(wsc + SLABB);
    float* S1 = (float*)(wsc + 2 * SLABB);
    float* S2 = (float*)(wsc + 3 * SLABB);
    unsigned short* Hb = (unsigned short*)S0;
    unsigned short* Xb = (unsigned short*)(wsc + 4 * SLABB);
    unsigned short* Yb = (unsigned short*)(wsc + 4 * SLABB + SLABB / 2);
    unsigned short* Wb = (unsigned short*)(wsc + 5 * SLABB);   // 24 MB

    embed_kernel<<<BATCH * TCTX, 256, 0, stream>>>(
        states, rtgs, meta, c1w, c1b, c2w, c2b, c3w, c3b, encw, encb,
        mw1, mb1, mw2, mb2, retw, retb, aemb, pos, gpos, actions, timesteps, X);

    const dim3 gqkv(24, 24);
    const dim3 g1024(8, 24);
    const dim3 g4096(32, 24);
    const dim3 gattn(12, NHEAD, BATCH);

    for (int i = 0; i < 6; ++i) {
        const size_t wOff = (size_t)i * C_DIM * C_DIM;
        const size_t bOff = (size_t)i * C_DIM;
        const size_t m1Off = (size_t)i * C_DIM * DFF;

        transpose_w_kernel<<<3072, 256, 0, stream>>>(
            Wq + wOff, Wk + wOff, Wv + wOff, Wo + wOff, Wm1 + m1Off, Wm2 + m1Off, Wb);

        ln_bf16_kernel<<<MROWS, 256, 0, stream>>>(X, Xb, ln1g + bOff, ln1b + bOff);
        mfma_gemm_qkv<<<gqkv, 256, 0, stream>>>(
            Xb, Wb, bq + bOff, bk + bOff, bv + bOff, S0);
        attn_flash<<<gattn, 256, 0, stream>>>(S0, S1, S2, Yb);
        mfma_gemm<0, 0, 1><<<g1024, 256, 0, stream>>>(
            Yb, Wb + (size_t)3 * 1048576, bo + bOff, X, X, nullptr, C_DIM, C_DIM);
        ln_bf16_kernel<<<MROWS, 256, 0, stream>>>(X, Xb, ln2g + bOff, ln2b + bOff);
        mfma_gemm<1, 1, 0><<<g4096, 256, 0, stream>>>(
            Xb, Wb + (size_t)4 * 1048576, bm1 + (size_t)i * DFF, nullptr, nullptr, Hb, DFF, C_DIM);
        mfma_gemm<0, 0, 1><<<g1024, 256, 0, stream>>>(
            Hb, Wb + (size_t)8 * 1048576, bm2 + bOff, X, X, nullptr, C_DIM, DFF);
    }

    ln_bf16_kernel<<<MROWS, 256, 0, stream>>>(X, Xb, lnfg, lnfb);
    head_kernel<<<BATCH * TCTX, 256, 0, stream>>>(Xb, hw, out);
}